// Round 1
// baseline (527.500 us; speedup 1.0000x reference)
//
#include <hip/hip_runtime.h>

#define HW3600 3600
#define NF4 3240000          // 3600*3600/4
#define NBINS 8192
#define CAP 16384
#define KSEL 100

// cm = softmax_col * softmax_row = exp(v)^2 / (den_row[l] * den_col[s])
// (no max subtraction: |sm| <= ~6, no overflow possible). Shared by hist
// and collect passes so values are bit-identical.
__device__ __forceinline__ float cm_of(float v, float dr, float dc) {
    float e = expf(v);
    return (e * e) / (dr * dc);
}

// ---------------- Pass A: fp32 GEMM sm = (f0 @ f1^T)/12.8 + exp-sum stats ----
// A[d][l] = x[batch, d, l], B[d][s] = x[batch+4, d, s]; sm[l,s] = sum_d A*B.
// 128x128 tile, 256 threads, 8x8 per thread, BK=16.
__global__ __launch_bounds__(256) void gemm_stats_k(
    const float* __restrict__ x, float* __restrict__ sm,
    float* __restrict__ den_row, float* __restrict__ den_col, int b0)
{
    const int bz = blockIdx.z;
    const int batch = b0 + bz;
    const float* __restrict__ A = x + (size_t)batch * 128 * HW3600;
    const float* __restrict__ B = x + (size_t)(batch + 4) * 128 * HW3600;
    float* __restrict__ smb = sm + (size_t)bz * HW3600 * HW3600;

    __shared__ __align__(16) float As[16][128];
    __shared__ __align__(16) float Bs[16][128];
    __shared__ float rowsum[128], colsum[128];

    const int lbase = blockIdx.y * 128;
    const int sbase = blockIdx.x * 128;
    const int tid = threadIdx.x;
    const int tx = tid & 15;   // s direction
    const int ty = tid >> 4;   // l direction

    float acc[8][8];
#pragma unroll
    for (int i = 0; i < 8; i++)
#pragma unroll
        for (int j = 0; j < 8; j++) acc[i][j] = 0.f;

    for (int k0 = 0; k0 < 128; k0 += 16) {
#pragma unroll
        for (int r = 0; r < 2; r++) {
            int i = tid + 256 * r;           // 0..511 float4 slots
            int kk = i >> 5;                 // 0..15
            int c = (i & 31) << 2;           // 0..124
            const float* arow = A + (size_t)(k0 + kk) * HW3600;
            const float* brow = B + (size_t)(k0 + kk) * HW3600;
            float4 av, bv;
            int l = lbase + c;
            if (l + 3 < HW3600) av = *(const float4*)(arow + l);
            else {
                float t0 = (l     < HW3600) ? arow[l]     : 0.f;
                float t1 = (l + 1 < HW3600) ? arow[l + 1] : 0.f;
                float t2 = (l + 2 < HW3600) ? arow[l + 2] : 0.f;
                float t3 = (l + 3 < HW3600) ? arow[l + 3] : 0.f;
                av = make_float4(t0, t1, t2, t3);
            }
            int s = sbase + c;
            if (s + 3 < HW3600) bv = *(const float4*)(brow + s);
            else {
                float t0 = (s     < HW3600) ? brow[s]     : 0.f;
                float t1 = (s + 1 < HW3600) ? brow[s + 1] : 0.f;
                float t2 = (s + 2 < HW3600) ? brow[s + 2] : 0.f;
                float t3 = (s + 3 < HW3600) ? brow[s + 3] : 0.f;
                bv = make_float4(t0, t1, t2, t3);
            }
            *(float4*)&As[kk][c] = av;
            *(float4*)&Bs[kk][c] = bv;
        }
        __syncthreads();
#pragma unroll
        for (int kk = 0; kk < 16; kk++) {
            float a[8], b[8];
            *(float4*)&a[0] = *(const float4*)&As[kk][ty * 4];
            *(float4*)&a[4] = *(const float4*)&As[kk][ty * 4 + 64];
            *(float4*)&b[0] = *(const float4*)&Bs[kk][tx * 4];
            *(float4*)&b[4] = *(const float4*)&Bs[kk][tx * 4 + 64];
#pragma unroll
            for (int i = 0; i < 8; i++)
#pragma unroll
                for (int j = 0; j < 8; j++)
                    acc[i][j] = fmaf(a[i], b[j], acc[i][j]);
        }
        __syncthreads();
    }

    // ---- epilogue: scale, store sm, accumulate exp sums ----
    if (tid < 128) { rowsum[tid] = 0.f; colsum[tid] = 0.f; }
    __syncthreads();
    const float scale = 0.078125f;  // 1/12.8 (uniform scale; ordering-invariant)
    float csum[8] = {0, 0, 0, 0, 0, 0, 0, 0};
#pragma unroll
    for (int i = 0; i < 8; i++) {
        int li = ty * 4 + ((i < 4) ? i : (64 + i - 4));
        int l = lbase + li;
        if (l >= HW3600) continue;
        float* orow = smb + (size_t)l * HW3600;
        float vv[8];
        float rs = 0.f;
#pragma unroll
        for (int j = 0; j < 8; j++) {
            int s = sbase + tx * 4 + ((j < 4) ? j : (64 + j - 4));
            float v = acc[i][j] * scale;
            vv[j] = v;
            if (s < HW3600) { float e = expf(v); rs += e; csum[j] += e; }
        }
        int s0 = sbase + tx * 4;
        if (s0 + 3 < HW3600) *(float4*)(orow + s0) = make_float4(vv[0], vv[1], vv[2], vv[3]);
        else { for (int u = 0; u < 4; u++) if (s0 + u < HW3600) orow[s0 + u] = vv[u]; }
        int s1 = s0 + 64;
        if (s1 + 3 < HW3600) *(float4*)(orow + s1) = make_float4(vv[4], vv[5], vv[6], vv[7]);
        else { for (int u = 0; u < 4; u++) if (s1 + u < HW3600) orow[s1 + u] = vv[u]; }
        atomicAdd(&rowsum[li], rs);
    }
#pragma unroll
    for (int j = 0; j < 8; j++) {
        int sj = tx * 4 + ((j < 4) ? j : (64 + j - 4));
        if (sbase + sj < HW3600) atomicAdd(&colsum[sj], csum[j]);
    }
    __syncthreads();
    if (tid < 128) {
        int l = lbase + tid;
        if (l < HW3600) atomicAdd(&den_row[(size_t)batch * HW3600 + l], rowsum[tid]);
        int s = sbase + tid;
        if (s < HW3600) atomicAdd(&den_col[(size_t)batch * HW3600 + s], colsum[tid]);
    }
}

// ---------------- Pass B: histogram of cm (float-bit bins, monotone) --------
__global__ __launch_bounds__(256) void hist_k(
    const float* __restrict__ sm, const float* __restrict__ den_row,
    const float* __restrict__ den_col, unsigned* __restrict__ hist, int b0)
{
    int bz = blockIdx.z, batch = b0 + bz;
    const float4* smb = (const float4*)(sm + (size_t)bz * HW3600 * HW3600);
    const float* dr = den_row + (size_t)batch * HW3600;
    const float4* dc4 = (const float4*)(den_col + (size_t)batch * HW3600);
    __shared__ unsigned h[NBINS];
    for (int i = threadIdx.x; i < NBINS; i += 256) h[i] = 0u;
    __syncthreads();
    int stride = gridDim.x * 256;
    for (int f = blockIdx.x * 256 + threadIdx.x; f < NF4; f += stride) {
        float4 v = smb[f];
        int row = f / 900;              // 900 float4 per sm row (3600/4)
        float drv = dr[row];
        float4 dcv = dc4[f - row * 900];
        unsigned c0 = __float_as_uint(cm_of(v.x, drv, dcv.x)) >> 19;
        unsigned c1 = __float_as_uint(cm_of(v.y, drv, dcv.y)) >> 19;
        unsigned c2 = __float_as_uint(cm_of(v.z, drv, dcv.z)) >> 19;
        unsigned c3 = __float_as_uint(cm_of(v.w, drv, dcv.w)) >> 19;
        atomicAdd(&h[c0], 1u); atomicAdd(&h[c1], 1u);
        atomicAdd(&h[c2], 1u); atomicAdd(&h[c3], 1u);
    }
    __syncthreads();
    unsigned* gh = hist + (size_t)batch * NBINS;
    for (int i = threadIdx.x; i < NBINS; i += 256) {
        unsigned c = h[i];
        if (c) atomicAdd(&gh[i], c);
    }
}

// ---------------- Pass C: find threshold bin (cumulative from top >= 100) ---
__global__ __launch_bounds__(256) void thresh_k(
    const unsigned* __restrict__ hist, int* __restrict__ thr, int b0)
{
    int batch = b0 + blockIdx.z;
    const unsigned* gh = hist + (size_t)batch * NBINS;
    __shared__ unsigned h[NBINS];
    __shared__ unsigned pc[256];
    int tid = threadIdx.x;
    for (int i = tid; i < NBINS; i += 256) h[i] = gh[i];
    __syncthreads();
    unsigned s = 0;
    for (int j = 0; j < 32; j++) s += h[tid * 32 + j];
    pc[tid] = s;
    __syncthreads();
    if (tid == 0) {
        unsigned cum = 0;
        int chunk = 255;
        for (; chunk >= 0; chunk--) {
            if (cum + pc[chunk] >= (unsigned)KSEL) break;
            cum += pc[chunk];
        }
        int bin = 0;
        if (chunk >= 0) {
            for (bin = chunk * 32 + 31; bin >= chunk * 32; bin--) {
                cum += h[bin];
                if (cum >= (unsigned)KSEL) break;
            }
            if (bin < chunk * 32) bin = chunk * 32;
        }
        thr[batch] = bin;
    }
}

// ---------------- Pass D: collect candidates >= threshold bin ---------------
__global__ __launch_bounds__(256) void collect_k(
    const float* __restrict__ sm, const float* __restrict__ den_row,
    const float* __restrict__ den_col, const int* __restrict__ thr,
    uint2* __restrict__ cand, int* __restrict__ cnt, int b0)
{
    int bz = blockIdx.z, batch = b0 + bz;
    const float4* smb = (const float4*)(sm + (size_t)bz * HW3600 * HW3600);
    const float* dr = den_row + (size_t)batch * HW3600;
    const float4* dc4 = (const float4*)(den_col + (size_t)batch * HW3600);
    uint2* cb = cand + (size_t)batch * CAP;
    int* cc = cnt + batch;
    unsigned tb = (unsigned)thr[batch];
    int stride = gridDim.x * 256;
    for (int f = blockIdx.x * 256 + threadIdx.x; f < NF4; f += stride) {
        float4 v = smb[f];
        int row = f / 900;
        float drv = dr[row];
        float4 dcv = dc4[f - row * 900];
        float cm[4];
        cm[0] = cm_of(v.x, drv, dcv.x);
        cm[1] = cm_of(v.y, drv, dcv.y);
        cm[2] = cm_of(v.z, drv, dcv.z);
        cm[3] = cm_of(v.w, drv, dcv.w);
#pragma unroll
        for (int u = 0; u < 4; u++) {
            unsigned bits = __float_as_uint(cm[u]);
            if ((bits >> 19) >= tb) {
                int pos = atomicAdd(cc, 1);
                if (pos < CAP) cb[pos] = make_uint2(bits, (unsigned)(f * 4 + u));
            }
        }
    }
}

// ---------------- Pass E: exact ordered top-100 + fold coords into W --------
// key = (val_bits << 32) | ~idx  -> max = largest value, tie = lowest index
// (matches lax.top_k tie rule). Then C0[d] = sum_k coords0_k . W[d,2k:2k+2].
__global__ __launch_bounds__(256) void select_k(
    uint2* __restrict__ cand, const int* __restrict__ cnt,
    const float* __restrict__ W,
    float* __restrict__ C0, float* __restrict__ C1,
    float* __restrict__ Sx, float* __restrict__ Sy, int b0)
{
    int batch = b0 + blockIdx.z;
    int tid = threadIdx.x;
    uint2* cb = cand + (size_t)batch * CAP;
    int M = cnt[batch];
    if (M > CAP) M = CAP;

    __shared__ uint2 lc[2048];
    __shared__ int topiS[KSEL];
    __shared__ unsigned long long wmax[4];
    __shared__ int wpos[4];
    __shared__ float cx0S[KSEL], cy0S[KSEL], cx1S[KSEL], cy1S[KSEL];

    bool useL = (M <= 2048);
    if (useL) for (int i = tid; i < M; i += 256) lc[i] = cb[i];
    __syncthreads();

    for (int r = 0; r < KSEL; r++) {
        unsigned long long bk = 0ull; int bp = -1;
        for (int i = tid; i < M; i += 256) {
            uint2 e = useL ? lc[i] : cb[i];
            if (e.x == 0u) continue;  // marked (cm>0 always -> bits!=0 when live)
            unsigned long long key = ((unsigned long long)e.x << 32) | (unsigned)(~e.y);
            if (key > bk) { bk = key; bp = i; }
        }
#pragma unroll
        for (int off = 1; off < 64; off <<= 1) {
            unsigned long long ok = __shfl_xor(bk, off);
            int op = __shfl_xor(bp, off);
            if (ok > bk) { bk = ok; bp = op; }
        }
        if ((tid & 63) == 0) { wmax[tid >> 6] = bk; wpos[tid >> 6] = bp; }
        __syncthreads();
        if (tid == 0) {
            unsigned long long fk = wmax[0]; int fp = wpos[0];
            for (int w = 1; w < 4; w++) if (wmax[w] > fk) { fk = wmax[w]; fp = wpos[w]; }
            uint2 e = useL ? lc[fp] : cb[fp];
            topiS[r] = (int)e.y;
            if (useL) lc[fp].x = 0u; else cb[fp].x = 0u;
        }
        __syncthreads();
    }

    if (tid < KSEL) {
        int idx = topiS[tid];
        int q = idx / 3600, rr = idx - q * 3600;
        cx0S[tid] = (float)(q % 60) / 60.0f;
        cy0S[tid] = (float)(q / 60) / 60.0f;
        cx1S[tid] = (float)(rr % 60) / 60.0f;
        cy1S[tid] = (float)(rr / 60) / 60.0f;
    }
    __syncthreads();
    if (tid < 128) {
        const float* wr = W + tid * 200;
        float c0 = 0.f, c1 = 0.f, sx = 0.f, sy = 0.f;
        for (int k = 0; k < KSEL; k++) {
            float wx = wr[2 * k], wy = wr[2 * k + 1];
            c0 += cx0S[k] * wx + cy0S[k] * wy;
            c1 += cx1S[k] * wx + cy1S[k] * wy;
            sx += wx; sy += wy;
        }
        C0[batch * 128 + tid] = c0;
        C1[batch * 128 + tid] = c1;
        if (batch == 0) { Sx[tid] = sx; Sy[tid] = sy; }
    }
}

// ---------------- Pass F: out = x + emb (elementwise, input layout) ---------
// emb[b,d,p] = bias[d] - C[b][d] + (gx_p)*Sx[d] + (gy_p)*Sy[d]
__global__ __launch_bounds__(256) void final_k(
    const float* __restrict__ x, const float* __restrict__ bias,
    const float* __restrict__ C0, const float* __restrict__ C1,
    const float* __restrict__ Sx, const float* __restrict__ Sy,
    float* __restrict__ out)
{
    int bd = blockIdx.x;            // 0..1023 = b*128 + d
    int b = bd >> 7, d = bd & 127;
    float cst = bias[d] - ((b < 4) ? C0[b * 128 + d] : C1[(b - 4) * 128 + d]);
    float sx = Sx[d], sy = Sy[d];
    const float4* xin = (const float4*)(x + (size_t)bd * HW3600);
    float4* o4 = (float4*)(out + (size_t)bd * HW3600);
    for (int f = threadIdx.x; f < 900; f += 256) {
        float4 v = xin[f];
        int p0 = f * 4;
        float gy = (float)(p0 / 60) / 60.0f;   // 60%4==0: same row for all 4
        float gxb = (float)(p0 % 60);
        float add = cst + gy * sy;
        v.x += add + ((gxb        ) / 60.0f) * sx;
        v.y += add + ((gxb + 1.0f) / 60.0f) * sx;
        v.z += add + ((gxb + 2.0f) / 60.0f) * sx;
        v.w += add + ((gxb + 3.0f) / 60.0f) * sx;
        o4[f] = v;
    }
}

extern "C" void kernel_launch(void* const* d_in, const int* in_sizes, int n_in,
                              void* d_out, int out_size, void* d_ws, size_t ws_size,
                              hipStream_t stream)
{
    const float* x    = (const float*)d_in[0];   // (8,128,3600)
    const float* W    = (const float*)d_in[1];   // (128,200)
    const float* bias = (const float*)d_in[2];   // (128)
    float* out = (float*)d_out;

    char* ws = (char*)d_ws;
    float*    den_row = (float*)(ws + 0);          // 4*3600 f
    float*    den_col = (float*)(ws + 57600);      // 4*3600 f
    unsigned* hist    = (unsigned*)(ws + 115200);  // 4*8192 u32
    int*      thr     = (int*)(ws + 246272);       // 4
    int*      cnt     = (int*)(ws + 246288);       // 4
    float*    C0      = (float*)(ws + 246304);     // 4*128
    float*    C1      = (float*)(ws + 248352);     // 4*128
    float*    Sx      = (float*)(ws + 250400);     // 128
    float*    Sy      = (float*)(ws + 250912);     // 128
    uint2*    cand    = (uint2*)(ws + 262144);     // 4*CAP uint2
    float*    sm      = (float*)(ws + 1048576);    // nslot * 51,840,000 B

    const size_t smBytes = (size_t)HW3600 * HW3600 * 4;
    int nslot = (ws_size >= 1048576 + 4 * smBytes) ? 4 : 1;

    // zero den_row/den_col/hist/thr/cnt (ws is poisoned 0xAA each call)
    hipMemsetAsync(d_ws, 0, 246304, stream);

    for (int b0 = 0; b0 < 4; b0 += nslot) {
        gemm_stats_k<<<dim3(29, 29, nslot), 256, 0, stream>>>(x, sm, den_row, den_col, b0);
        hist_k    <<<dim3(320, 1, nslot), 256, 0, stream>>>(sm, den_row, den_col, hist, b0);
        thresh_k  <<<dim3(1,   1, nslot), 256, 0, stream>>>(hist, thr, b0);
        collect_k <<<dim3(320, 1, nslot), 256, 0, stream>>>(sm, den_row, den_col, thr, cand, cnt, b0);
        select_k  <<<dim3(1,   1, nslot), 256, 0, stream>>>(cand, cnt, W, C0, C1, Sx, Sy, b0);
    }
    final_k<<<dim3(1024), 256, 0, stream>>>(x, bias, C0, C1, Sx, Sy, out);
}

// Round 2
// 386.117 us; speedup vs baseline: 1.3662x; 1.3662x over previous
//
#include <hip/hip_runtime.h>

#define HW 3600
#define PADR 3712            // 29*128, zero-padded rows in transposed bf16 buffers
#define NF4 900              // float4 per sm row
#define CAP 131072
#define KSEL 100
typedef unsigned long long U64;

using short8  = __attribute__((ext_vector_type(8))) short;
using float4v = __attribute__((ext_vector_type(4))) float;

// monotone map: float -> u32 preserving order for all finite values
__device__ __forceinline__ unsigned monof(float f) {
    unsigned b = __float_as_uint(f);
    return (b & 0x80000000u) ? ~b : (b | 0x80000000u);
}
__device__ __forceinline__ float unmonof(unsigned m) {
    return __uint_as_float((m & 0x80000000u) ? (m ^ 0x80000000u) : ~m);
}
__device__ __forceinline__ unsigned short f2bf(float f) {   // RNE
    unsigned b = __float_as_uint(f);
    return (unsigned short)((b + 0x7FFFu + ((b >> 16) & 1u)) >> 16);
}
__device__ __forceinline__ float bf2f(unsigned short h) {
    return __uint_as_float(((unsigned)h) << 16);
}

// ---- Pass 0: convert x (b,d,l) -> transposed split-bf16 hiT/loT (b,l,d) ----
__global__ __launch_bounds__(256) void conv_k(
    const float* __restrict__ x,
    unsigned short* __restrict__ hiT, unsigned short* __restrict__ loT)
{
    int b = blockIdx.z, l0 = blockIdx.x * 64, d0 = blockIdx.y * 64;
    __shared__ float t[64][65];
    int tid = threadIdx.x;
#pragma unroll
    for (int r = 0; r < 4; r++) {
        int idx = tid + 256 * r;              // 1024 float4 slots
        int d = idx >> 4, lq = idx & 15;
        int l = l0 + lq * 4;
        const float* src = x + ((size_t)b * 128 + d0 + d) * HW;
        float4 v;
        if (l + 3 < HW) v = *(const float4*)(src + l);
        else {
            v.x = (l     < HW) ? src[l]     : 0.f;
            v.y = (l + 1 < HW) ? src[l + 1] : 0.f;
            v.z = (l + 2 < HW) ? src[l + 2] : 0.f;
            v.w = (l + 3 < HW) ? src[l + 3] : 0.f;
        }
        t[lq * 4 + 0][d] = v.x; t[lq * 4 + 1][d] = v.y;
        t[lq * 4 + 2][d] = v.z; t[lq * 4 + 3][d] = v.w;
    }
    __syncthreads();
#pragma unroll
    for (int r = 0; r < 2; r++) {
        int idx = tid + 256 * r;              // 512 chunks of 8 bf16
        int l = idx >> 3, dq = idx & 7;
        unsigned hp[4], lp[4];
#pragma unroll
        for (int j = 0; j < 4; j++) {
            float f0 = t[l][dq * 8 + 2 * j], f1 = t[l][dq * 8 + 2 * j + 1];
            unsigned short h0 = f2bf(f0), h1 = f2bf(f1);
            unsigned short g0 = f2bf(f0 - bf2f(h0)), g1 = f2bf(f1 - bf2f(h1));
            hp[j] = (unsigned)h0 | ((unsigned)h1 << 16);
            lp[j] = (unsigned)g0 | ((unsigned)g1 << 16);
        }
        size_t o = ((size_t)b * PADR + l0 + l) * 128 + d0 + dq * 8;
        *(uint4*)(hiT + o) = make_uint4(hp[0], hp[1], hp[2], hp[3]);
        *(uint4*)(loT + o) = make_uint4(lp[0], lp[1], lp[2], lp[3]);
    }
}

// ---- Pass A: split-bf16 3xMFMA GEMM + exp-sums + per-row (max,argmax) ------
__global__ __launch_bounds__(256) void gemm_mfma_k(
    const unsigned short* __restrict__ hiT, const unsigned short* __restrict__ loT,
    float* __restrict__ sm, float* __restrict__ den_row, float* __restrict__ den_col,
    U64* __restrict__ rowmax, int b0)
{
    const int bz = blockIdx.z, batch = b0 + bz;
    const unsigned short* Ah = hiT + (size_t)batch * PADR * 128;
    const unsigned short* Al = loT + (size_t)batch * PADR * 128;
    const unsigned short* Bh = hiT + (size_t)(batch + 4) * PADR * 128;
    const unsigned short* Bl = loT + (size_t)(batch + 4) * PADR * 128;
    float* __restrict__ smb = sm + (size_t)bz * HW * HW;

    __shared__ __align__(16) unsigned short sA[2][4][128][8];
    __shared__ __align__(16) unsigned short sB[2][4][128][8];
    __shared__ float rowsumS[128], colsumS[128];
    __shared__ U64 rowmaxS[128];

    const int tid = threadIdx.x;
    const int lane = tid & 63, w = tid >> 6;
    const int wr = w >> 1, wc = w & 1;
    const int m = lane & 15, q = lane >> 4;

    if (tid < 128) { rowsumS[tid] = 0.f; colsumS[tid] = 0.f; rowmaxS[tid] = 0ull; }

    float4v acc[4][4];
#pragma unroll
    for (int i = 0; i < 4; i++)
#pragma unroll
        for (int j = 0; j < 4; j++) acc[i][j] = (float4v){0.f, 0.f, 0.f, 0.f};

    for (int k0 = 0; k0 < 128; k0 += 32) {
        __syncthreads();
#pragma unroll
        for (int r = 0; r < 8; r++) {
            int ch = tid + 256 * r;          // 2048 chunks of 16 B
            int part = ch >> 9, c = ch & 511;
            int l = c >> 2, kb = c & 3;
            const unsigned short* src = (part == 0) ? Ah : (part == 1) ? Al
                                      : (part == 2) ? Bh : Bl;
            int rowbase = (part < 2) ? blockIdx.y * 128 : blockIdx.x * 128;
            uint4 v = *(const uint4*)(src + (size_t)(rowbase + l) * 128 + k0 + kb * 8);
            unsigned short* dst = (part == 0) ? &sA[0][kb][l][0] : (part == 1) ? &sA[1][kb][l][0]
                                : (part == 2) ? &sB[0][kb][l][0] : &sB[1][kb][l][0];
            *(uint4*)dst = v;
        }
        __syncthreads();
        short8 ah[4], al[4], bh[4], bl[4];
#pragma unroll
        for (int t = 0; t < 4; t++) {
            ah[t] = *(const short8*)&sA[0][q][wr * 64 + t * 16 + m][0];
            al[t] = *(const short8*)&sA[1][q][wr * 64 + t * 16 + m][0];
            bh[t] = *(const short8*)&sB[0][q][wc * 64 + t * 16 + m][0];
            bl[t] = *(const short8*)&sB[1][q][wc * 64 + t * 16 + m][0];
        }
#pragma unroll
        for (int mt = 0; mt < 4; mt++)
#pragma unroll
            for (int nt = 0; nt < 4; nt++) {
                acc[mt][nt] = __builtin_amdgcn_mfma_f32_16x16x32_bf16(ah[mt], bh[nt], acc[mt][nt], 0, 0, 0);
                acc[mt][nt] = __builtin_amdgcn_mfma_f32_16x16x32_bf16(ah[mt], bl[nt], acc[mt][nt], 0, 0, 0);
                acc[mt][nt] = __builtin_amdgcn_mfma_f32_16x16x32_bf16(al[mt], bh[nt], acc[mt][nt], 0, 0, 0);
            }
    }

    // ---- epilogue ----
    const int lbw = blockIdx.y * 128 + wr * 64;
    const int sbw = blockIdx.x * 128 + wc * 64;
    float colpart[4] = {0.f, 0.f, 0.f, 0.f};
    float rowpart[4][4];
    U64   rowmk[4][4];
#pragma unroll
    for (int i = 0; i < 4; i++)
#pragma unroll
        for (int r = 0; r < 4; r++) { rowpart[i][r] = 0.f; rowmk[i][r] = 0ull; }

#pragma unroll
    for (int mt = 0; mt < 4; mt++)
#pragma unroll
        for (int nt = 0; nt < 4; nt++) {
            int s = sbw + nt * 16 + m;
            bool sv = (s < HW);
#pragma unroll
            for (int r = 0; r < 4; r++) {
                int l = lbw + mt * 16 + q * 4 + r;
                float v = acc[mt][nt][r] * 0.078125f;   // 1/(128*0.1)
                bool lv = (l < HW);
                if (lv && sv) smb[(size_t)l * HW + s] = v;
                float e = __expf(v);
                if (sv) {
                    rowpart[mt][r] += e;
                    U64 pk = ((U64)monof(v) << 32) | (unsigned)s;
                    if (pk > rowmk[mt][r]) rowmk[mt][r] = pk;
                }
                if (lv) colpart[nt] += e;
            }
        }
    // reduce rows across the 16 m-lanes
#pragma unroll
    for (int mt = 0; mt < 4; mt++)
#pragma unroll
        for (int r = 0; r < 4; r++) {
            float v = rowpart[mt][r];
            U64 pk = rowmk[mt][r];
#pragma unroll
            for (int off = 1; off < 16; off <<= 1) {
                v += __shfl_xor(v, off);
                U64 o = __shfl_xor(pk, off);
                if (o > pk) pk = o;
            }
            if (m == 0) {
                int lr = wr * 64 + mt * 16 + q * 4 + r;
                atomicAdd(&rowsumS[lr], v);
                atomicMax(&rowmaxS[lr], pk);
            }
        }
    // reduce cols across the 4 quads
#pragma unroll
    for (int nt = 0; nt < 4; nt++) {
        float v = colpart[nt];
        v += __shfl_xor(v, 16);
        v += __shfl_xor(v, 32);
        if (q == 0) atomicAdd(&colsumS[wc * 64 + nt * 16 + m], v);
    }
    __syncthreads();
    if (tid < 128) {
        int l = blockIdx.y * 128 + tid;
        if (l < HW) {
            atomicAdd(&den_row[(size_t)batch * HW + l], rowsumS[tid]);
            atomicMax(&rowmax[(size_t)batch * HW + l], rowmaxS[tid]);
        }
        int s = blockIdx.x * 128 + tid;
        if (s < HW) atomicAdd(&den_col[(size_t)batch * HW + s], colsumS[tid]);
    }
}

// ---- Pass B: logs, exact tau (100th of per-row-argmax keys), row pruning ---
__global__ __launch_bounds__(256) void prep_k(
    const float* __restrict__ den_row, const float* __restrict__ den_col,
    const U64* __restrict__ rowmax,
    float* __restrict__ lnDr, float* __restrict__ lnDc,
    float* __restrict__ tau, int* __restrict__ rowlist, int* __restrict__ rowcnt, int b0)
{
    int batch = b0 + blockIdx.z;
    int tid = threadIdx.x;
    __shared__ float ldrS[HW];
    __shared__ float lncS[HW];
    __shared__ float ubS[HW];
    __shared__ float wminS[4];
    __shared__ U64 wmaxS[4];
    __shared__ U64 bestS;
    __shared__ float lminS, tauS;
    __shared__ int rcS;

    float lmin = 3.4e38f;
    for (int i = tid; i < HW; i += 256) {
        float ldr = __logf(den_row[(size_t)batch * HW + i]);
        float ldc = __logf(den_col[(size_t)batch * HW + i]);
        lnDr[(size_t)batch * HW + i] = ldr;
        lnDc[(size_t)batch * HW + i] = ldc;
        ldrS[i] = ldr; lncS[i] = ldc;
        lmin = fminf(lmin, ldc);
    }
#pragma unroll
    for (int off = 1; off < 64; off <<= 1) lmin = fminf(lmin, __shfl_xor(lmin, off));
    if ((tid & 63) == 0) wminS[tid >> 6] = lmin;
    __syncthreads();
    if (tid == 0) {
        lminS = fminf(fminf(wminS[0], wminS[1]), fminf(wminS[2], wminS[3]));
        rcS = 0;
    }
    __syncthreads();
    float lm = lminS;

    U64 kk[15];
    int nk = 0;
    for (int i = tid; i < HW; i += 256) {
        U64 rm = rowmax[(size_t)batch * HW + i];
        unsigned mo = (unsigned)(rm >> 32);
        unsigned col = (unsigned)(rm & 0xffffffffu);
        float mv = unmonof(mo);
        float key = 2.0f * mv - ldrS[i] - lncS[col];
        float ub  = 2.0f * mv - ldrS[i] - lm;
        ubS[i] = ub;
        kk[nk++] = ((U64)monof(key) << 32) | (unsigned)i;
    }
    for (int j = nk; j < 15; j++) kk[j] = 0ull;
    __syncthreads();

    for (int r = 0; r < KSEL; r++) {
        U64 bk = 0ull;
#pragma unroll
        for (int j = 0; j < 15; j++) if (kk[j] > bk) bk = kk[j];
#pragma unroll
        for (int off = 1; off < 64; off <<= 1) { U64 o = __shfl_xor(bk, off); if (o > bk) bk = o; }
        if ((tid & 63) == 0) wmaxS[tid >> 6] = bk;
        __syncthreads();
        if (tid == 0) {
            U64 b_ = wmaxS[0];
            for (int ww = 1; ww < 4; ww++) if (wmaxS[ww] > b_) b_ = wmaxS[ww];
            bestS = b_;
            if (r == KSEL - 1) tauS = unmonof((unsigned)(b_ >> 32));
        }
        __syncthreads();
        U64 b_ = bestS;
#pragma unroll
        for (int j = 0; j < 15; j++) if (kk[j] == b_) kk[j] = 0ull;
        __syncthreads();
    }
    float tv = tauS;
    for (int i = tid; i < HW; i += 256)
        if (ubS[i] >= tv) {
            int p = atomicAdd(&rcS, 1);
            rowlist[(size_t)batch * HW + p] = i;
        }
    __syncthreads();
    if (tid == 0) { rowcnt[batch] = rcS; tau[batch] = tv; }
}

// ---- Pass C: collect candidates t >= tau over pruned rows ------------------
__global__ __launch_bounds__(256) void collect_k(
    const float* __restrict__ sm, const float* __restrict__ lnDr,
    const float* __restrict__ lnDc, const float* __restrict__ tau,
    const int* __restrict__ rowlist, const int* __restrict__ rowcnt,
    uint2* __restrict__ cand, int* __restrict__ cnt, int b0)
{
    int bz = blockIdx.z, batch = b0 + bz;
    int rcq = rowcnt[batch];
    int r0 = blockIdx.x * 16;
    if (r0 >= rcq) return;
    float tv = tau[batch];
    const float* smb = sm + (size_t)bz * HW * HW;
    const float4* lc4 = (const float4*)(lnDc + (size_t)batch * HW);
    uint2* cb = cand + (size_t)batch * CAP;
    for (int rj = 0; rj < 16; rj++) {
        int ri = r0 + rj;
        if (ri >= rcq) break;
        int row = rowlist[(size_t)batch * HW + ri];
        float ldr = lnDr[(size_t)batch * HW + row];
        const float4* rp = (const float4*)(smb + (size_t)row * HW);
        for (int f = threadIdx.x; f < NF4; f += 256) {
            float4 v = rp[f];
            float4 lv = lc4[f];
            float t0 = 2.0f * v.x - ldr - lv.x;
            float t1 = 2.0f * v.y - ldr - lv.y;
            float t2 = 2.0f * v.z - ldr - lv.z;
            float t3 = 2.0f * v.w - ldr - lv.w;
            unsigned base = (unsigned)(row * HW + f * 4);
            if (t0 >= tv) { int p = atomicAdd(&cnt[batch], 1); if (p < CAP) cb[p] = make_uint2(monof(t0), base); }
            if (t1 >= tv) { int p = atomicAdd(&cnt[batch], 1); if (p < CAP) cb[p] = make_uint2(monof(t1), base + 1); }
            if (t2 >= tv) { int p = atomicAdd(&cnt[batch], 1); if (p < CAP) cb[p] = make_uint2(monof(t2), base + 2); }
            if (t3 >= tv) { int p = atomicAdd(&cnt[batch], 1); if (p < CAP) cb[p] = make_uint2(monof(t3), base + 3); }
        }
    }
}

// ---- Pass D: exact ordered top-100 + fold coords into W --------------------
__global__ __launch_bounds__(256) void select_k(
    uint2* __restrict__ cand, const int* __restrict__ cnt,
    const float* __restrict__ W,
    float* __restrict__ C0, float* __restrict__ C1,
    float* __restrict__ Sx, float* __restrict__ Sy, int b0)
{
    int batch = b0 + blockIdx.z;
    int tid = threadIdx.x;
    uint2* cb = cand + (size_t)batch * CAP;
    int M = cnt[batch];
    if (M > CAP) M = CAP;

    __shared__ uint2 lc[6144];
    __shared__ int topiS[KSEL];
    __shared__ U64 wmax[4];
    __shared__ int wpos[4];
    __shared__ float cx0S[KSEL], cy0S[KSEL], cx1S[KSEL], cy1S[KSEL];

    bool useL = (M <= 6144);
    if (useL) for (int i = tid; i < M; i += 256) lc[i] = cb[i];
    __syncthreads();

    for (int r = 0; r < KSEL; r++) {
        U64 bk = 0ull; int bp = -1;
        for (int i = tid; i < M; i += 256) {
            uint2 e = useL ? lc[i] : cb[i];
            if (e.x == 0u) continue;
            U64 key = ((U64)e.x << 32) | (unsigned)(~e.y);
            if (key > bk) { bk = key; bp = i; }
        }
#pragma unroll
        for (int off = 1; off < 64; off <<= 1) {
            U64 ok = __shfl_xor(bk, off);
            int op = __shfl_xor(bp, off);
            if (ok > bk) { bk = ok; bp = op; }
        }
        if ((tid & 63) == 0) { wmax[tid >> 6] = bk; wpos[tid >> 6] = bp; }
        __syncthreads();
        if (tid == 0) {
            U64 fk = wmax[0]; int fp = wpos[0];
            for (int ww = 1; ww < 4; ww++) if (wmax[ww] > fk) { fk = wmax[ww]; fp = wpos[ww]; }
            uint2 e = useL ? lc[fp] : cb[fp];
            topiS[r] = (int)e.y;
            if (useL) lc[fp].x = 0u; else cb[fp].x = 0u;
        }
        __syncthreads();
    }

    if (tid < KSEL) {
        int idx = topiS[tid];
        int qq = idx / HW, rr = idx - qq * HW;
        cx0S[tid] = (float)(qq % 60) / 60.0f;
        cy0S[tid] = (float)(qq / 60) / 60.0f;
        cx1S[tid] = (float)(rr % 60) / 60.0f;
        cy1S[tid] = (float)(rr / 60) / 60.0f;
    }
    __syncthreads();
    if (tid < 128) {
        const float* wr_ = W + tid * 200;
        float c0 = 0.f, c1 = 0.f, sx = 0.f, sy = 0.f;
        for (int k = 0; k < KSEL; k++) {
            float wx = wr_[2 * k], wy = wr_[2 * k + 1];
            c0 += cx0S[k] * wx + cy0S[k] * wy;
            c1 += cx1S[k] * wx + cy1S[k] * wy;
            sx += wx; sy += wy;
        }
        C0[batch * 128 + tid] = c0;
        C1[batch * 128 + tid] = c1;
        if (batch == 0) { Sx[tid] = sx; Sy[tid] = sy; }
    }
}

// ---- Pass E: out = x + affine emb (elementwise) ----------------------------
__global__ __launch_bounds__(256) void final_k(
    const float* __restrict__ x, const float* __restrict__ bias,
    const float* __restrict__ C0, const float* __restrict__ C1,
    const float* __restrict__ Sx, const float* __restrict__ Sy,
    float* __restrict__ out)
{
    int bd = blockIdx.x;
    int b = bd >> 7, d = bd & 127;
    float cst = bias[d] - ((b < 4) ? C0[b * 128 + d] : C1[(b - 4) * 128 + d]);
    float sx = Sx[d], sy = Sy[d];
    const float4* xin = (const float4*)(x + (size_t)bd * HW);
    float4* o4 = (float4*)(out + (size_t)bd * HW);
    for (int f = threadIdx.x; f < NF4; f += 256) {
        float4 v = xin[f];
        int p0 = f * 4;
        float gy = (float)(p0 / 60) / 60.0f;
        float gxb = (float)(p0 % 60);
        float add = cst + gy * sy;
        v.x += add + ((gxb       ) / 60.0f) * sx;
        v.y += add + ((gxb + 1.f) / 60.0f) * sx;
        v.z += add + ((gxb + 2.f) / 60.0f) * sx;
        v.w += add + ((gxb + 3.f) / 60.0f) * sx;
        o4[f] = v;
    }
}

extern "C" void kernel_launch(void* const* d_in, const int* in_sizes, int n_in,
                              void* d_out, int out_size, void* d_ws, size_t ws_size,
                              hipStream_t stream)
{
    const float* x    = (const float*)d_in[0];
    const float* W    = (const float*)d_in[1];
    const float* bias = (const float*)d_in[2];
    float* out = (float*)d_out;

    char* ws = (char*)d_ws;
    float*    den_row = (float*)(ws + 0);          // 4*3600*4 = 57600
    float*    den_col = (float*)(ws + 57600);      // 57600       -> 115200
    U64*      rowmax  = (U64*)  (ws + 115200);     // 4*3600*8    -> 230400
    int*      cnt     = (int*)  (ws + 230400);     // 16
    float*    tau     = (float*)(ws + 230416);     // 16
    int*      rowcnt  = (int*)  (ws + 230432);     // 16          -> 230448
    float*    lnDr    = (float*)(ws + 230464);     // 57600       -> 288064
    float*    lnDc    = (float*)(ws + 288064);     // 57600       -> 345664
    int*      rowlist = (int*)  (ws + 345664);     // 57600       -> 403264
    float*    C0      = (float*)(ws + 403264);     // 2048
    float*    C1      = (float*)(ws + 405312);     // 2048
    float*    Sx      = (float*)(ws + 407360);     // 512
    float*    Sy      = (float*)(ws + 407872);     // 512         -> 408384
    uint2*    cand    = (uint2*)(ws + 408448);     // 4*CAP*8 = 4194304 -> 4602752
    unsigned short* hiT = (unsigned short*)(ws + 4602752);   // 8*3712*128*2 = 7602176 -> 12204928
    unsigned short* loT = (unsigned short*)(ws + 12204928);  // 7602176 -> 19807104
    float*    sm      = (float*)(ws + 19807104);   // nslot * 51840000

    const size_t smBytes = (size_t)HW * HW * 4;
    const size_t base = 19807104;
    int nslot = 1;
    if (ws_size >= base + 4 * smBytes) nslot = 4;
    else if (ws_size >= base + 2 * smBytes) nslot = 2;

    hipMemsetAsync(d_ws, 0, 230464, stream);

    conv_k<<<dim3(58, 2, 8), 256, 0, stream>>>(x, hiT, loT);

    for (int b0 = 0; b0 < 4; b0 += nslot) {
        gemm_mfma_k<<<dim3(29, 29, nslot), 256, 0, stream>>>(hiT, loT, sm, den_row, den_col, rowmax, b0);
        prep_k    <<<dim3(1, 1, nslot), 256, 0, stream>>>(den_row, den_col, rowmax, lnDr, lnDc, tau, rowlist, rowcnt, b0);
        collect_k <<<dim3(225, 1, nslot), 256, 0, stream>>>(sm, lnDr, lnDc, tau, rowlist, rowcnt, cand, cnt, b0);
        select_k  <<<dim3(1, 1, nslot), 256, 0, stream>>>(cand, cnt, W, C0, C1, Sx, Sy, b0);
    }
    final_k<<<dim3(1024), 256, 0, stream>>>(x, bias, C0, C1, Sx, Sy, out);
}

// Round 3
// 290.679 us; speedup vs baseline: 1.8147x; 1.3283x over previous
//
#include <hip/hip_runtime.h>

#define HW 3600
#define PADR 3712            // 29*128, zero-padded rows in transposed bf16 buffers
#define NF4 900              // float4 per x row
#define CAP 131072
#define KSEL 100
typedef unsigned long long U64;

using short8  = __attribute__((ext_vector_type(8))) short;
using float4v = __attribute__((ext_vector_type(4))) float;

// monotone map: float -> u32 preserving order for all finite values
__device__ __forceinline__ unsigned monof(float f) {
    unsigned b = __float_as_uint(f);
    return (b & 0x80000000u) ? ~b : (b | 0x80000000u);
}
__device__ __forceinline__ float unmonof(unsigned m) {
    return __uint_as_float((m & 0x80000000u) ? (m ^ 0x80000000u) : ~m);
}
__device__ __forceinline__ unsigned short f2bf(float f) {   // RNE
    unsigned b = __float_as_uint(f);
    return (unsigned short)((b + 0x7FFFu + ((b >> 16) & 1u)) >> 16);
}
__device__ __forceinline__ float bf2f(unsigned short h) {
    return __uint_as_float(((unsigned)h) << 16);
}

// ---- Pass 0: convert x (b,d,l) -> transposed split-bf16 hiT/loT (b,l,d) ----
__global__ __launch_bounds__(256) void conv_k(
    const float* __restrict__ x,
    unsigned short* __restrict__ hiT, unsigned short* __restrict__ loT)
{
    int b = blockIdx.z, l0 = blockIdx.x * 64, d0 = blockIdx.y * 64;
    __shared__ float t[64][65];
    int tid = threadIdx.x;
#pragma unroll
    for (int r = 0; r < 4; r++) {
        int idx = tid + 256 * r;              // 1024 float4 slots
        int d = idx >> 4, lq = idx & 15;
        int l = l0 + lq * 4;
        const float* src = x + ((size_t)b * 128 + d0 + d) * HW;
        float4 v;
        if (l + 3 < HW) v = *(const float4*)(src + l);
        else {
            v.x = (l     < HW) ? src[l]     : 0.f;
            v.y = (l + 1 < HW) ? src[l + 1] : 0.f;
            v.z = (l + 2 < HW) ? src[l + 2] : 0.f;
            v.w = (l + 3 < HW) ? src[l + 3] : 0.f;
        }
        t[lq * 4 + 0][d] = v.x; t[lq * 4 + 1][d] = v.y;
        t[lq * 4 + 2][d] = v.z; t[lq * 4 + 3][d] = v.w;
    }
    __syncthreads();
#pragma unroll
    for (int r = 0; r < 2; r++) {
        int idx = tid + 256 * r;              // 512 chunks of 8 bf16
        int l = idx >> 3, dq = idx & 7;
        unsigned hp[4], lp[4];
#pragma unroll
        for (int j = 0; j < 4; j++) {
            float f0 = t[l][dq * 8 + 2 * j], f1 = t[l][dq * 8 + 2 * j + 1];
            unsigned short h0 = f2bf(f0), h1 = f2bf(f1);
            unsigned short g0 = f2bf(f0 - bf2f(h0)), g1 = f2bf(f1 - bf2f(h1));
            hp[j] = (unsigned)h0 | ((unsigned)h1 << 16);
            lp[j] = (unsigned)g0 | ((unsigned)g1 << 16);
        }
        size_t o = ((size_t)b * PADR + l0 + l) * 128 + d0 + dq * 8;
        *(uint4*)(hiT + o) = make_uint4(hp[0], hp[1], hp[2], hp[3]);
        *(uint4*)(loT + o) = make_uint4(lp[0], lp[1], lp[2], lp[3]);
    }
}

// ---- Pass A: split-bf16 3xMFMA GEMM -> exp-sums + per-row (max,argmax) -----
// NO sm materialization: only den_row, den_col, rowmax leave this kernel.
__global__ __launch_bounds__(256) void gemm_mfma_k(
    const unsigned short* __restrict__ hiT, const unsigned short* __restrict__ loT,
    float* __restrict__ den_row, float* __restrict__ den_col,
    U64* __restrict__ rowmax, int b0)
{
    const int batch = b0 + blockIdx.z;
    const unsigned short* Ah = hiT + (size_t)batch * PADR * 128;
    const unsigned short* Al = loT + (size_t)batch * PADR * 128;
    const unsigned short* Bh = hiT + (size_t)(batch + 4) * PADR * 128;
    const unsigned short* Bl = loT + (size_t)(batch + 4) * PADR * 128;

    __shared__ __align__(16) unsigned short sA[2][4][128][8];
    __shared__ __align__(16) unsigned short sB[2][4][128][8];
    __shared__ float rowsumS[128], colsumS[128];
    __shared__ U64 rowmaxS[128];

    const int tid = threadIdx.x;
    const int lane = tid & 63, w = tid >> 6;
    const int wr = w >> 1, wc = w & 1;
    const int m = lane & 15, q = lane >> 4;

    if (tid < 128) { rowsumS[tid] = 0.f; colsumS[tid] = 0.f; rowmaxS[tid] = 0ull; }

    float4v acc[4][4];
#pragma unroll
    for (int i = 0; i < 4; i++)
#pragma unroll
        for (int j = 0; j < 4; j++) acc[i][j] = (float4v){0.f, 0.f, 0.f, 0.f};

    for (int k0 = 0; k0 < 128; k0 += 32) {
        __syncthreads();
#pragma unroll
        for (int r = 0; r < 8; r++) {
            int ch = tid + 256 * r;          // 2048 chunks of 16 B
            int part = ch >> 9, c = ch & 511;
            int l = c >> 2, kb = c & 3;
            const unsigned short* src = (part == 0) ? Ah : (part == 1) ? Al
                                      : (part == 2) ? Bh : Bl;
            int rowbase = (part < 2) ? blockIdx.y * 128 : blockIdx.x * 128;
            uint4 v = *(const uint4*)(src + (size_t)(rowbase + l) * 128 + k0 + kb * 8);
            unsigned short* dst = (part == 0) ? &sA[0][kb][l][0] : (part == 1) ? &sA[1][kb][l][0]
                                : (part == 2) ? &sB[0][kb][l][0] : &sB[1][kb][l][0];
            *(uint4*)dst = v;
        }
        __syncthreads();
        short8 ah[4], al[4], bh[4], bl[4];
#pragma unroll
        for (int t = 0; t < 4; t++) {
            ah[t] = *(const short8*)&sA[0][q][wr * 64 + t * 16 + m][0];
            al[t] = *(const short8*)&sA[1][q][wr * 64 + t * 16 + m][0];
            bh[t] = *(const short8*)&sB[0][q][wc * 64 + t * 16 + m][0];
            bl[t] = *(const short8*)&sB[1][q][wc * 64 + t * 16 + m][0];
        }
#pragma unroll
        for (int mt = 0; mt < 4; mt++)
#pragma unroll
            for (int nt = 0; nt < 4; nt++) {
                acc[mt][nt] = __builtin_amdgcn_mfma_f32_16x16x32_bf16(ah[mt], bh[nt], acc[mt][nt], 0, 0, 0);
                acc[mt][nt] = __builtin_amdgcn_mfma_f32_16x16x32_bf16(ah[mt], bl[nt], acc[mt][nt], 0, 0, 0);
                acc[mt][nt] = __builtin_amdgcn_mfma_f32_16x16x32_bf16(al[mt], bh[nt], acc[mt][nt], 0, 0, 0);
            }
    }

    // ---- epilogue: stats only, no stores of sm ----
    const int lbw = blockIdx.y * 128 + wr * 64;
    const int sbw = blockIdx.x * 128 + wc * 64;
    float colpart[4] = {0.f, 0.f, 0.f, 0.f};
    float rowpart[4][4];
    U64   rowmk[4][4];
#pragma unroll
    for (int i = 0; i < 4; i++)
#pragma unroll
        for (int r = 0; r < 4; r++) { rowpart[i][r] = 0.f; rowmk[i][r] = 0ull; }

#pragma unroll
    for (int mt = 0; mt < 4; mt++)
#pragma unroll
        for (int nt = 0; nt < 4; nt++) {
            int s = sbw + nt * 16 + m;
            bool sv = (s < HW);
#pragma unroll
            for (int r = 0; r < 4; r++) {
                int l = lbw + mt * 16 + q * 4 + r;
                float v = acc[mt][nt][r] * 0.078125f;   // 1/(128*0.1)
                bool lv = (l < HW);
                float e = __expf(v);
                if (sv) {
                    rowpart[mt][r] += e;
                    U64 pk = ((U64)monof(v) << 32) | (unsigned)s;
                    if (pk > rowmk[mt][r]) rowmk[mt][r] = pk;
                }
                if (lv) colpart[nt] += e;
            }
        }
#pragma unroll
    for (int mt = 0; mt < 4; mt++)
#pragma unroll
        for (int r = 0; r < 4; r++) {
            float v = rowpart[mt][r];
            U64 pk = rowmk[mt][r];
#pragma unroll
            for (int off = 1; off < 16; off <<= 1) {
                v += __shfl_xor(v, off);
                U64 o = __shfl_xor(pk, off);
                if (o > pk) pk = o;
            }
            if (m == 0) {
                int lr = wr * 64 + mt * 16 + q * 4 + r;
                atomicAdd(&rowsumS[lr], v);
                atomicMax(&rowmaxS[lr], pk);
            }
        }
#pragma unroll
    for (int nt = 0; nt < 4; nt++) {
        float v = colpart[nt];
        v += __shfl_xor(v, 16);
        v += __shfl_xor(v, 32);
        if (q == 0) atomicAdd(&colsumS[wc * 64 + nt * 16 + m], v);
    }
    __syncthreads();
    if (tid < 128) {
        int l = blockIdx.y * 128 + tid;
        if (l < HW) {
            atomicAdd(&den_row[(size_t)batch * HW + l], rowsumS[tid]);
            atomicMax(&rowmax[(size_t)batch * HW + l], rowmaxS[tid]);
        }
        int s = blockIdx.x * 128 + tid;
        if (s < HW) atomicAdd(&den_col[(size_t)batch * HW + s], colsumS[tid]);
    }
}

// ---- Pass B: logs, exact tau via 32-bit binary search, row pruning ---------
__global__ __launch_bounds__(256) void prep_k(
    const float* __restrict__ den_row, const float* __restrict__ den_col,
    const U64* __restrict__ rowmax,
    float* __restrict__ lnDr, float* __restrict__ lnDc,
    float* __restrict__ tau, int* __restrict__ rowlist, int* __restrict__ rowcnt, int b0)
{
    const int batch = b0 + blockIdx.z;
    const int tid = threadIdx.x;
    __shared__ float ldrS[HW];
    __shared__ float lncS[HW];
    __shared__ float ubS[HW];
    __shared__ unsigned keyS[HW];   // reuses nothing; 4*14400 B total ~57.6 KB
    __shared__ float wminS[4];
    __shared__ unsigned wcntS[4];
    __shared__ float lminS;
    __shared__ unsigned tmS;
    __shared__ int rcS;

    float lmin = 3.4e38f;
    for (int i = tid; i < HW; i += 256) {
        float ldr = __logf(den_row[(size_t)batch * HW + i]);
        float ldc = __logf(den_col[(size_t)batch * HW + i]);
        lnDr[(size_t)batch * HW + i] = ldr;
        lnDc[(size_t)batch * HW + i] = ldc;
        ldrS[i] = ldr; lncS[i] = ldc;
        lmin = fminf(lmin, ldc);
    }
#pragma unroll
    for (int off = 1; off < 64; off <<= 1) lmin = fminf(lmin, __shfl_xor(lmin, off));
    if ((tid & 63) == 0) wminS[tid >> 6] = lmin;
    __syncthreads();
    if (tid == 0) {
        lminS = fminf(fminf(wminS[0], wminS[1]), fminf(wminS[2], wminS[3]));
        tmS = 0u; rcS = 0;
    }
    __syncthreads();
    float lm = lminS;

    for (int i = tid; i < HW; i += 256) {
        U64 rm = rowmax[(size_t)batch * HW + i];
        float mv = unmonof((unsigned)(rm >> 32));
        unsigned col = (unsigned)(rm & 0xffffffffu);
        float key = 2.0f * mv - ldrS[i] - lncS[col];
        ubS[i]  = 2.0f * mv - ldrS[i] - lm;
        keyS[i] = monof(key);
    }
    __syncthreads();

    // binary search: largest m with count(keyS >= m) >= KSEL  == 100th-largest
    for (int bit = 31; bit >= 0; bit--) {
        unsigned candm = tmS | (1u << bit);
        unsigned c = 0;
        for (int i = tid; i < HW; i += 256) c += (keyS[i] >= candm) ? 1u : 0u;
#pragma unroll
        for (int off = 1; off < 64; off <<= 1) c += __shfl_xor(c, off);
        if ((tid & 63) == 0) wcntS[tid >> 6] = c;
        __syncthreads();
        if (tid == 0) {
            unsigned tc = wcntS[0] + wcntS[1] + wcntS[2] + wcntS[3];
            if (tc >= (unsigned)KSEL) tmS = candm;
        }
        __syncthreads();
    }
    // slack: covers 1-ulp FP-contraction drift of the same expression across
    // kernels; only ever ADDS candidates (select is exact), never drops.
    float tv = unmonof(tmS) - 1e-4f;
    for (int i = tid; i < HW; i += 256)
        if (ubS[i] >= tv) {
            int p = atomicAdd(&rcS, 1);
            rowlist[(size_t)batch * HW + p] = i;
        }
    __syncthreads();
    if (tid == 0) { rowcnt[batch] = rcS; tau[batch] = tv; }
}

// ---- Pass C: recompute pruned rows (bit-identical MFMA chain) + collect ----
__global__ __launch_bounds__(256) void recollect_k(
    const unsigned short* __restrict__ hiT, const unsigned short* __restrict__ loT,
    const float* __restrict__ lnDr, const float* __restrict__ lnDc,
    const float* __restrict__ tau, const int* __restrict__ rowlist,
    const int* __restrict__ rowcnt, uint2* __restrict__ cand,
    int* __restrict__ cnt, int b0)
{
    const int batch = b0 + blockIdx.z;
    const int rcq = rowcnt[batch];
    const int g = blockIdx.y;                 // group of 16 pruned rows
    if (g * 16 >= rcq) return;
    const float tv = tau[batch];

    __shared__ int rowS[16];
    __shared__ float ldrS[16];
    const int tid = threadIdx.x;
    if (tid < 16) {
        int ri = g * 16 + tid;
        int row = (ri < rcq) ? rowlist[(size_t)batch * HW + ri] : HW; // HW row is zero pad
        rowS[tid] = row;
        ldrS[tid] = (ri < rcq) ? lnDr[(size_t)batch * HW + row] : 0.f;
    }
    __syncthreads();

    const unsigned short* Ah = hiT + (size_t)batch * PADR * 128;
    const unsigned short* Al = loT + (size_t)batch * PADR * 128;
    const unsigned short* Bh = hiT + (size_t)(batch + 4) * PADR * 128;
    const unsigned short* Bl = loT + (size_t)(batch + 4) * PADR * 128;

    const int lane = tid & 63, w = tid >> 6;
    const int m = lane & 15, q = lane >> 4;
    const size_t aoff = (size_t)rowS[m] * 128 + q * 8;
    const int colb = blockIdx.x * 128 + w * 32;

    float4v acc[2];
    acc[0] = (float4v){0.f, 0.f, 0.f, 0.f};
    acc[1] = (float4v){0.f, 0.f, 0.f, 0.f};
#pragma unroll
    for (int k0 = 0; k0 < 128; k0 += 32) {
        short8 ah = *(const short8*)(Ah + aoff + k0);
        short8 al = *(const short8*)(Al + aoff + k0);
#pragma unroll
        for (int nt = 0; nt < 2; nt++) {
            size_t boff = (size_t)(colb + nt * 16 + m) * 128 + (size_t)(q * 8 + k0);
            short8 bh = *(const short8*)(Bh + boff);
            short8 bl = *(const short8*)(Bl + boff);
            acc[nt] = __builtin_amdgcn_mfma_f32_16x16x32_bf16(ah, bh, acc[nt], 0, 0, 0);
            acc[nt] = __builtin_amdgcn_mfma_f32_16x16x32_bf16(ah, bl, acc[nt], 0, 0, 0);
            acc[nt] = __builtin_amdgcn_mfma_f32_16x16x32_bf16(al, bh, acc[nt], 0, 0, 0);
        }
    }
#pragma unroll
    for (int nt = 0; nt < 2; nt++) {
        int col = colb + nt * 16 + m;
        if (col >= HW) continue;
        float ldc = lnDc[(size_t)batch * HW + col];
#pragma unroll
        for (int r = 0; r < 4; r++) {
            int ridx = q * 4 + r;
            if (g * 16 + ridx >= rcq) continue;
            float v = acc[nt][r] * 0.078125f;
            float t = 2.0f * v - ldrS[ridx] - ldc;
            if (t >= tv) {
                int p = atomicAdd(&cnt[batch], 1);
                if (p < CAP)
                    cand[(size_t)batch * CAP + p] =
                        make_uint2(monof(t), (unsigned)(rowS[ridx] * HW + col));
            }
        }
    }
}

// ---- Pass D: exact top-100 via 64-bit key binary search + rank, fold W -----
__global__ __launch_bounds__(256) void select_k(
    const uint2* __restrict__ cand, const int* __restrict__ cnt,
    const float* __restrict__ W,
    float* __restrict__ C0, float* __restrict__ C1,
    float* __restrict__ Sx, float* __restrict__ Sy, int b0)
{
    const int batch = b0 + blockIdx.z;
    const int tid = threadIdx.x;
    const uint2* cb = cand + (size_t)batch * CAP;
    int M = cnt[batch]; if (M > CAP) M = CAP;

    __shared__ uint2 lc[6144];
    __shared__ unsigned wcntS[4];
    __shared__ U64 tmS;
    __shared__ U64 selS[128];
    __shared__ int scS;
    __shared__ int topiS[KSEL];
    __shared__ float cx0S[KSEL], cy0S[KSEL], cx1S[KSEL], cy1S[KSEL];

    const bool useL = (M <= 6144);
    if (useL) for (int i = tid; i < M; i += 256) lc[i] = cb[i];
    if (tid == 0) { tmS = 0ull; scS = 0; }
    __syncthreads();

    // key = (mono_t << 32) | ~idx : unique; max-first = largest t, lowest idx
    for (int bit = 63; bit >= 0; bit--) {
        U64 candk = tmS | (1ull << bit);
        unsigned c = 0;
        for (int i = tid; i < M; i += 256) {
            uint2 e = useL ? lc[i] : cb[i];
            U64 key = ((U64)e.x << 32) | (unsigned)(~e.y);
            c += (key >= candk) ? 1u : 0u;
        }
#pragma unroll
        for (int off = 1; off < 64; off <<= 1) c += __shfl_xor(c, off);
        if ((tid & 63) == 0) wcntS[tid >> 6] = c;
        __syncthreads();
        if (tid == 0) {
            unsigned tc = wcntS[0] + wcntS[1] + wcntS[2] + wcntS[3];
            if (tc >= (unsigned)KSEL) tmS = candk;
        }
        __syncthreads();
    }
    U64 thr = tmS;   // exactly the 100th-largest key (keys unique)
    for (int i = tid; i < M; i += 256) {
        uint2 e = useL ? lc[i] : cb[i];
        U64 key = ((U64)e.x << 32) | (unsigned)(~e.y);
        if (key >= thr) {
            int p = atomicAdd(&scS, 1);
            if (p < 128) selS[p] = key;
        }
    }
    __syncthreads();
    int SC = scS; if (SC > 128) SC = 128;     // expected exactly 100
    if (tid < SC) {
        U64 my = selS[tid];
        int rank = 0;
        for (int j = 0; j < SC; j++) rank += (selS[j] > my) ? 1 : 0;
        if (rank < KSEL) topiS[rank] = (int)(~(unsigned)(my & 0xffffffffu));
    }
    __syncthreads();

    if (tid < KSEL) {
        int idx = topiS[tid];
        int qq = idx / HW, rr = idx - qq * HW;
        cx0S[tid] = (float)(qq % 60) / 60.0f;
        cy0S[tid] = (float)(qq / 60) / 60.0f;
        cx1S[tid] = (float)(rr % 60) / 60.0f;
        cy1S[tid] = (float)(rr / 60) / 60.0f;
    }
    __syncthreads();
    if (tid < 128) {
        const float* wr_ = W + tid * 200;
        float c0 = 0.f, c1 = 0.f, sx = 0.f, sy = 0.f;
        for (int k = 0; k < KSEL; k++) {
            float wx = wr_[2 * k], wy = wr_[2 * k + 1];
            c0 += cx0S[k] * wx + cy0S[k] * wy;
            c1 += cx1S[k] * wx + cy1S[k] * wy;
            sx += wx; sy += wy;
        }
        C0[batch * 128 + tid] = c0;
        C1[batch * 128 + tid] = c1;
        if (batch == 0) { Sx[tid] = sx; Sy[tid] = sy; }
    }
}

// ---- Pass E: out = x + affine emb (elementwise) ----------------------------
__global__ __launch_bounds__(256) void final_k(
    const float* __restrict__ x, const float* __restrict__ bias,
    const float* __restrict__ C0, const float* __restrict__ C1,
    const float* __restrict__ Sx, const float* __restrict__ Sy,
    float* __restrict__ out)
{
    int bd = blockIdx.x;
    int b = bd >> 7, d = bd & 127;
    float cst = bias[d] - ((b < 4) ? C0[b * 128 + d] : C1[(b - 4) * 128 + d]);
    float sx = Sx[d], sy = Sy[d];
    const float4* xin = (const float4*)(x + (size_t)bd * HW);
    float4* o4 = (float4*)(out + (size_t)bd * HW);
    for (int f = threadIdx.x; f < NF4; f += 256) {
        float4 v = xin[f];
        int p0 = f * 4;
        float gy = (float)(p0 / 60) / 60.0f;
        float gxb = (float)(p0 % 60);
        float add = cst + gy * sy;
        v.x += add + ((gxb       ) / 60.0f) * sx;
        v.y += add + ((gxb + 1.f) / 60.0f) * sx;
        v.z += add + ((gxb + 2.f) / 60.0f) * sx;
        v.w += add + ((gxb + 3.f) / 60.0f) * sx;
        o4[f] = v;
    }
}

extern "C" void kernel_launch(void* const* d_in, const int* in_sizes, int n_in,
                              void* d_out, int out_size, void* d_ws, size_t ws_size,
                              hipStream_t stream)
{
    const float* x    = (const float*)d_in[0];
    const float* W    = (const float*)d_in[1];
    const float* bias = (const float*)d_in[2];
    float* out = (float*)d_out;

    char* ws = (char*)d_ws;
    float*    den_row = (float*)(ws + 0);          // 57600
    float*    den_col = (float*)(ws + 57600);      // 57600   -> 115200
    U64*      rowmax  = (U64*)  (ws + 115200);     // 115200  -> 230400
    int*      cnt     = (int*)  (ws + 230400);     // 16
    int*      rowcnt  = (int*)  (ws + 230416);     // 16
    float*    tau     = (float*)(ws + 230432);     // 16      -> 230448
    float*    lnDr    = (float*)(ws + 230464);     // 57600   -> 288064
    float*    lnDc    = (float*)(ws + 288064);     // 57600   -> 345664
    int*      rowlist = (int*)  (ws + 345664);     // 57600   -> 403264
    float*    C0      = (float*)(ws + 403264);     // 2048
    float*    C1      = (float*)(ws + 405312);     // 2048
    float*    Sx      = (float*)(ws + 407360);     // 512
    float*    Sy      = (float*)(ws + 407872);     // 512     -> 408384
    uint2*    cand    = (uint2*)(ws + 408448);     // 4194304 -> 4602752
    unsigned short* hiT = (unsigned short*)(ws + 4602752);   // 7602176 -> 12204928
    unsigned short* loT = (unsigned short*)(ws + 12204928);  // 7602176 -> 19807104

    hipMemsetAsync(d_ws, 0, 230448, stream);       // den/rowmax/cnt/rowcnt/tau

    conv_k     <<<dim3(58, 2, 8),   256, 0, stream>>>(x, hiT, loT);
    gemm_mfma_k<<<dim3(29, 29, 4),  256, 0, stream>>>(hiT, loT, den_row, den_col, rowmax, 0);
    prep_k     <<<dim3(1, 1, 4),    256, 0, stream>>>(den_row, den_col, rowmax, lnDr, lnDc, tau, rowlist, rowcnt, 0);
    recollect_k<<<dim3(29, 225, 4), 256, 0, stream>>>(hiT, loT, lnDr, lnDc, tau, rowlist, rowcnt, cand, cnt, 0);
    select_k   <<<dim3(1, 1, 4),    256, 0, stream>>>(cand, cnt, W, C0, C1, Sx, Sy, 0);
    final_k    <<<dim3(1024),       256, 0, stream>>>(x, bias, C0, C1, Sx, Sy, out);
}